// Round 5
// baseline (317.585 us; speedup 1.0000x reference)
//
#include <hip/hip_runtime.h>
#include <hip/hip_fp16.h>

// Exact-CSR element-chunked scatter/gather:
//   count  : one pass over conn -> counts[chunk][bucket] (LDS hist + merge)
//   scan   : exclusive prefix per chunk -> offsets + cursors (exact, no slack)
//   fill(c): one pass over chunk's elements; compute force once; write 8B
//            self-contained records {fx16,fy16 | local16,fz16} at exact offsets
//   accum(c): block per bucket; LDS fp32 tile (init 0 / load F_int partial),
//            replay records, store partial; LAST chunk fuses the masked loss.
// Element data is streamed exactly once across all fills. No global float
// atomics. F_int partial precision (fp32/fp16) and chunk count K chosen from
// ws_size at launch (deterministic).

#define SPAN   1024
#define NBMAX  1024
#define CEPB   8       // count: elems/thread (1024 thr -> 8192 elems/block)
#define FEPB   4       // fill : elems/thread (256 thr  -> 1024 elems/block)

struct F3 { float x, y, z; };

__device__ __forceinline__ uint2 packrec(float fx, float fy, float fz, int local) {
    unsigned short hx = __half_as_ushort(__float2half(fx));
    unsigned short hy = __half_as_ushort(__float2half(fy));
    unsigned short hz = __half_as_ushort(__float2half(fz));
    return make_uint2(((unsigned)hy << 16) | hx, ((unsigned)local << 16) | hz);
}

__global__ void __launch_bounds__(1024)
count_kernel(const int2* __restrict__ conn, int* __restrict__ counts,
             int E, int chunkElems, int slabsPC, int NB) {
    __shared__ int hist[NBMAX];
    int c = blockIdx.x / slabsPC;
    int s = blockIdx.x - c * slabsPC;
    int base = c * chunkElems + s * (1024 * CEPB);
    int end  = (c + 1) * chunkElems;
    if (end > E) end = E;

    for (int b = threadIdx.x; b < NB; b += 1024) hist[b] = 0;
    __syncthreads();

    #pragma unroll
    for (int i = 0; i < CEPB; ++i) {
        int e = base + i * 1024 + threadIdx.x;
        if (e < end) {
            int2 cn = conn[e];
            atomicAdd(&hist[cn.x >> 10], 1);
            atomicAdd(&hist[cn.y >> 10], 1);
        }
    }
    __syncthreads();

    int* cc = counts + (size_t)c * NB;
    for (int b = threadIdx.x; b < NB; b += 1024) {
        int h = hist[b];
        if (h) atomicAdd(&cc[b], h);
    }
}

__global__ void __launch_bounds__(1024)
scan_kernel(const int* __restrict__ counts, int* __restrict__ offsets,
            int* __restrict__ cursors, int K, int NB) {
    __shared__ int sbuf[NBMAX];
    int tid = threadIdx.x;
    for (int c = 0; c < K; ++c) {
        int v = (tid < NB) ? counts[(size_t)c * NB + tid] : 0;
        sbuf[tid] = v;
        __syncthreads();
        for (int off = 1; off < NBMAX; off <<= 1) {
            int add = (tid >= off) ? sbuf[tid - off] : 0;
            __syncthreads();
            sbuf[tid] += add;
            __syncthreads();
        }
        if (tid < NB) {
            int excl = sbuf[tid] - v;
            offsets[(size_t)c * NB + tid] = excl;
            cursors[(size_t)c * NB + tid] = excl;
        }
        __syncthreads();
    }
}

__global__ void __launch_bounds__(256)
fill_kernel(const int2* __restrict__ conn,
            const F3*  __restrict__ pred,
            const float* __restrict__ u_c,
            const float* __restrict__ theta_c,
            const float* __restrict__ len,
            const float* __restrict__ pE,
            const float* __restrict__ pA,
            const float* __restrict__ pI,
            const float* __restrict__ dir,
            int* __restrict__ cursor,        // this chunk's cursor row
            uint2* __restrict__ lists,
            int cs, int ce, int NB) {
    __shared__ int hist[NBMAX];
    __shared__ int gbase[NBMAX];
    for (int b = threadIdx.x; b < NB; b += 256) hist[b] = 0;
    __syncthreads();

    float uc = u_c[0];
    float tc = theta_c[0];

    int blockStart = cs + blockIdx.x * (256 * FEPB);
    unsigned sv[2 * FEPB];   // (rank<<10)|bucket ; 0xFFFFFFFF = none
    uint2    rc[2 * FEPB];

    #pragma unroll
    for (int i = 0; i < FEPB; ++i) {
        int e = blockStart + i * 256 + threadIdx.x;
        unsigned sa = 0xFFFFFFFFu, sb = 0xFFFFFFFFu;
        if (e < ce) {
            int2 cn = conn[e];
            int na = cn.x, nb = cn.y;

            F3 pa_ = pred[na];
            F3 pb_ = pred[nb];

            float c  = dir[3 * e + 0];
            float s  = dir[3 * e + 2];
            float L  = len[e];
            float Ee = pE[e];
            float EA = Ee * pA[e];
            float EI = Ee * pI[e];

            float a0 = pa_.x * uc;
            float a1 = pa_.y * uc;
            float a2 = pa_.z * tc;
            float b0 = pb_.x * uc;
            float b1 = pb_.y * uc;
            float b2 = pb_.z * tc;

            float u_A  =  c * a0 + s * a1;
            float w_A  = -s * a0 + c * a1;
            float th_A = -a2;
            float u_B  =  c * b0 + s * b1;
            float w_B  = -s * b0 + c * b1;
            float th_B = -b2;

            float invL  = 1.0f / L;
            float ea_l  = EA * invL;            // AXIAL_WEIGHT = 1.0
            float ei_l  = EI * invL;
            float ei_l2 = ei_l  * invL;
            float ei_l3 = ei_l2 * invL;

            float dw = w_A - w_B;
            float f0 = ea_l * (u_A - u_B);
            float f1 = 12.0f * ei_l3 * dw + 6.0f * ei_l2 * (th_A + th_B);
            float f2 = 6.0f * ei_l2 * dw + 4.0f * ei_l * th_A + 2.0f * ei_l * th_B;
            float f5 = 6.0f * ei_l2 * dw + 2.0f * ei_l * th_A + 4.0f * ei_l * th_B;

            float fA0 = c * f0 - s * f1;
            float fA1 = s * f0 + c * f1;

            int bkA = na >> 10;
            int rA  = atomicAdd(&hist[bkA], 1);
            sa = ((unsigned)rA << 10) | (unsigned)bkA;
            rc[2 * i + 0] = packrec(fA0, fA1, -f2, na & 1023);

            int bkB = nb >> 10;
            int rB  = atomicAdd(&hist[bkB], 1);
            sb = ((unsigned)rB << 10) | (unsigned)bkB;
            rc[2 * i + 1] = packrec(-fA0, -fA1, -f5, nb & 1023);
        }
        sv[2 * i + 0] = sa;
        sv[2 * i + 1] = sb;
    }
    __syncthreads();

    for (int b = threadIdx.x; b < NB; b += 256) {
        int h = hist[b];
        gbase[b] = h ? atomicAdd(&cursor[b], h) : 0;
    }
    __syncthreads();

    #pragma unroll
    for (int j = 0; j < 2 * FEPB; ++j) {
        unsigned s = sv[j];
        if (s != 0xFFFFFFFFu) {
            int bk = (int)(s & 1023u);
            int r  = (int)(s >> 10);
            lists[(size_t)gbase[bk] + r] = rc[j];
        }
    }
}

__global__ void __launch_bounds__(512)
accum_kernel(const uint2* __restrict__ lists,
             const int* __restrict__ counts_c,
             const int* __restrict__ offsets_c,
             const float* __restrict__ Fext,
             const float* __restrict__ bcd,
             const float* __restrict__ bcr,
             double* __restrict__ acc,
             float* __restrict__ fint32,
             __half* __restrict__ fint16,
             int N, int isFirst, int isLast, int mode) {   // mode: 1 fp32, 2 fp16
    __shared__ float tile[SPAN * 3];
    __shared__ double sn[8], sd[8];

    int b = blockIdx.x;
    int nodeLo = b * SPAN;
    int gBase = nodeLo * 3;
    int gMax  = 3 * N;

    if (isFirst) {
        for (int i = threadIdx.x; i < SPAN * 3; i += 512) tile[i] = 0.0f;
    } else if (mode == 1) {
        for (int i = threadIdx.x; i < SPAN * 3; i += 512) {
            int g = gBase + i;
            tile[i] = (g < gMax) ? fint32[g] : 0.0f;
        }
    } else {
        for (int i = threadIdx.x; i < SPAN * 3; i += 512) {
            int g = gBase + i;
            tile[i] = (g < gMax) ? __half2float(fint16[g]) : 0.0f;
        }
    }
    __syncthreads();

    int cnt  = counts_c[b];
    int base = offsets_c[b];
    const uint2* L = lists + base;
    for (int r = threadIdx.x; r < cnt; r += 512) {
        uint2 rec = L[r];
        float fx = __half2float(__ushort_as_half((unsigned short)(rec.x & 0xFFFFu)));
        float fy = __half2float(__ushort_as_half((unsigned short)(rec.x >> 16)));
        float fz = __half2float(__ushort_as_half((unsigned short)(rec.y & 0xFFFFu)));
        int local = (int)(rec.y >> 16);
        atomicAdd(&tile[local * 3 + 0], fx);
        atomicAdd(&tile[local * 3 + 1], fy);
        atomicAdd(&tile[local * 3 + 2], fz);
    }
    __syncthreads();

    if (!isLast) {
        if (mode == 1) {
            for (int i = threadIdx.x; i < SPAN * 3; i += 512) {
                int g = gBase + i;
                if (g < gMax) fint32[g] = tile[i];
            }
        } else {
            for (int i = threadIdx.x; i < SPAN * 3; i += 512) {
                int g = gBase + i;
                if (g < gMax) fint16[g] = __float2half(tile[i]);
            }
        }
        return;
    }

    // fused masked loss over this bucket's node range
    int spanCnt = N - nodeLo;
    if (spanCnt > SPAN) spanCnt = SPAN;

    double num = 0.0, den = 0.0;
    for (int l = threadIdx.x; l < spanCnt; l += 512) {
        int n = nodeLo + l;
        float md = 1.0f - bcd[n];
        float mr = 1.0f - bcr[n];
        float e0 = Fext[3 * n + 0];
        float e1 = Fext[3 * n + 1];
        float e2 = Fext[3 * n + 2];
        float r0 = (tile[l * 3 + 0] - e0) * md;
        float r1 = (tile[l * 3 + 1] - e1) * md;
        float r2 = (tile[l * 3 + 2] - e2) * mr;
        float g0 = e0 * md;
        float g1 = e1 * md;
        float g2 = e2 * mr;
        num += (double)r0 * r0 + (double)r1 * r1 + (double)r2 * r2;
        den += (double)g0 * g0 + (double)g1 * g1 + (double)g2 * g2;
    }
    #pragma unroll
    for (int off = 32; off > 0; off >>= 1) {
        num += __shfl_down(num, off, 64);
        den += __shfl_down(den, off, 64);
    }
    int lane = threadIdx.x & 63;
    int wv   = threadIdx.x >> 6;
    if (lane == 0) { sn[wv] = num; sd[wv] = den; }
    __syncthreads();
    if (threadIdx.x == 0) {
        double tn = 0.0, td = 0.0;
        for (int w = 0; w < 8; ++w) { tn += sn[w]; td += sd[w]; }
        atomicAdd(&acc[0], tn);
        atomicAdd(&acc[1], td);
    }
}

__global__ void final_kernel(const double* __restrict__ acc, float* __restrict__ out) {
    double den = acc[1];
    if (den < 1e-30) den = 1e-30;
    out[0] = (float)(acc[0] / den);
}

static inline size_t align256(size_t x) { return (x + 255) & ~(size_t)255; }

extern "C" void kernel_launch(void* const* d_in, const int* in_sizes, int n_in,
                              void* d_out, int out_size, void* d_ws, size_t ws_size,
                              hipStream_t stream) {
    const F3*    pred    = (const F3*)d_in[0];
    const float* u_c     = (const float*)d_in[1];
    const float* theta_c = (const float*)d_in[2];
    const float* len     = (const float*)d_in[3];
    const float* pE      = (const float*)d_in[4];
    const float* pA      = (const float*)d_in[5];
    const float* pI      = (const float*)d_in[6];
    const float* dir     = (const float*)d_in[7];
    const float* Fext    = (const float*)d_in[8];
    const float* bcd     = (const float*)d_in[9];
    const float* bcr     = (const float*)d_in[10];
    const int2*  conn    = (const int2*)d_in[11];

    int N = in_sizes[0] / 3;
    int E = in_sizes[3];
    int NB = (N + SPAN - 1) / SPAN;   // 977 for N=1M (<= NBMAX)

    // Config ladder: (K chunks, partial mode: 0 none / 1 fp32 / 2 fp16)
    const int cfgK[7] = {1, 2, 2, 4, 4, 8, 16};
    const int cfgM[7] = {0, 1, 2, 1, 2, 2, 2};
    int K = 16, mode = 2;
    size_t offF = 0, offL = 0;
    for (int t = 0; t < 7; ++t) {
        int Kc = cfgK[t], Mc = cfgM[t];
        int ce = (E + Kc - 1) / Kc;
        size_t meta = 256 + (size_t)3 * Kc * NB * 4;
        size_t oF = align256(meta);
        size_t fb = (Kc > 1) ? (size_t)3 * N * (Mc == 1 ? 4 : 2) : 0;
        size_t oL = align256(oF + fb);
        size_t need = oL + (size_t)2 * ce * 8;
        if (need <= ws_size) { K = Kc; mode = Mc; offF = oF; offL = oL; break; }
        if (t == 6) { K = Kc; mode = Mc; offF = oF; offL = oL; }  // last resort
    }

    int chunkElems = (E + K - 1) / K;

    double* acc     = (double*)d_ws;
    int*    counts  = (int*)((char*)d_ws + 256);
    int*    offsets = counts + (size_t)K * NB;
    int*    cursors = offsets + (size_t)K * NB;
    float*  fint32  = (float*)((char*)d_ws + offF);
    __half* fint16  = (__half*)((char*)d_ws + offF);
    uint2*  lists   = (uint2*)((char*)d_ws + offL);

    // zero acc + counts in one memset
    hipMemsetAsync(d_ws, 0, 256 + (size_t)K * NB * 4, stream);

    int slabsPC = (chunkElems + 1024 * CEPB - 1) / (1024 * CEPB);
    count_kernel<<<K * slabsPC, 1024, 0, stream>>>(conn, counts, E, chunkElems, slabsPC, NB);

    scan_kernel<<<1, 1024, 0, stream>>>(counts, offsets, cursors, K, NB);

    for (int c = 0; c < K; ++c) {
        int cs = c * chunkElems;
        if (cs >= E) break;
        int ce = cs + chunkElems;
        if (ce > E) ce = E;
        int nfb = (ce - cs + 256 * FEPB - 1) / (256 * FEPB);

        fill_kernel<<<nfb, 256, 0, stream>>>(
            conn, pred, u_c, theta_c, len, pE, pA, pI, dir,
            cursors + (size_t)c * NB, lists, cs, ce, NB);

        int isFirst = (c == 0);
        int isLast  = (ce == E);
        accum_kernel<<<NB, 512, 0, stream>>>(
            lists, counts + (size_t)c * NB, offsets + (size_t)c * NB,
            Fext, bcd, bcr, acc, fint32, fint16, N, isFirst, isLast, mode);
    }

    final_kernel<<<1, 1, 0, stream>>>(acc, (float*)d_out);
}

// Round 6
// 305.574 us; speedup vs baseline: 1.0393x; 1.0393x over previous
//
#include <hip/hip_runtime.h>
#include <hip/hip_fp16.h>

// Exact-CSR element-chunked scatter/gather, LDS-staged coalesced fill.
//   count  : conn pass -> counts[chunk][bucket] (LDS hist, fire-and-forget merge)
//   scan   : exclusive prefix per chunk -> offsets + cursors
//   fill(c): block owns FBE=4096 elems. Pass1: LDS hist over all elems, ONE
//            cursor atomic per (block,bucket). Then 2 stages of 2048 elems:
//            compute force once, rank via LDS hist, block scan, scatter records
//            into LDS slab grouped by bucket, flush coalesced to exact global
//            CSR positions. Records: 8B {fx16,fy16 | local16,fz16}.
//   accum(c): block per 1024-node bucket; LDS fp32 tile; replay records;
//            last chunk fuses the masked loss. No global float atomics.
// Requires NB <= 1024 (N <= 1M nodes at SPAN=1024). K and partial precision
// picked from ws_size (deterministic).

#define SPAN   1024
#define NBMAX  1024
#define CEPB   8        // count: elems/thread (1024 thr -> 8192/block)
#define FTH    1024     // fill threads
#define FBE    4096     // fill: elems per block
#define FSTG   2048     // fill: elems per stage (2 stages)

struct F3 { float x, y, z; };

__device__ __forceinline__ uint2 packrec(float fx, float fy, float fz, int local) {
    unsigned short hx = __half_as_ushort(__float2half(fx));
    unsigned short hy = __half_as_ushort(__float2half(fy));
    unsigned short hz = __half_as_ushort(__float2half(fz));
    return make_uint2(((unsigned)hy << 16) | hx, ((unsigned)local << 16) | hz);
}

__global__ void __launch_bounds__(1024)
count_kernel(const int2* __restrict__ conn, int* __restrict__ counts,
             int E, int chunkElems, int slabsPC, int NB) {
    __shared__ int hist[NBMAX];
    int c = blockIdx.x / slabsPC;
    int s = blockIdx.x - c * slabsPC;
    int base = c * chunkElems + s * (1024 * CEPB);
    int end  = (c + 1) * chunkElems;
    if (end > E) end = E;

    for (int b = threadIdx.x; b < NBMAX; b += 1024) hist[b] = 0;
    __syncthreads();

    #pragma unroll
    for (int i = 0; i < CEPB; ++i) {
        int e = base + i * 1024 + threadIdx.x;
        if (e < end) {
            int2 cn = conn[e];
            atomicAdd(&hist[cn.x >> 10], 1);
            atomicAdd(&hist[cn.y >> 10], 1);
        }
    }
    __syncthreads();

    int* cc = counts + (size_t)c * NB;
    for (int b = threadIdx.x; b < NB; b += 1024) {
        int h = hist[b];
        if (h) atomicAdd(&cc[b], h);   // fire-and-forget
    }
}

__global__ void __launch_bounds__(1024)
scan_kernel(const int* __restrict__ counts, int* __restrict__ offsets,
            int* __restrict__ cursors, int K, int NB) {
    __shared__ int sbuf[NBMAX];
    int tid = threadIdx.x;
    for (int c = 0; c < K; ++c) {
        int v = (tid < NB) ? counts[(size_t)c * NB + tid] : 0;
        sbuf[tid] = v;
        __syncthreads();
        for (int off = 1; off < NBMAX; off <<= 1) {
            int add = (tid >= off) ? sbuf[tid - off] : 0;
            __syncthreads();
            sbuf[tid] += add;
            __syncthreads();
        }
        if (tid < NB) {
            int excl = sbuf[tid] - v;
            offsets[(size_t)c * NB + tid] = excl;
            cursors[(size_t)c * NB + tid] = excl;
        }
        __syncthreads();
    }
}

__global__ void __launch_bounds__(1024, 8)
fill_kernel(const int2* __restrict__ conn,
            const F3*  __restrict__ pred,
            const float* __restrict__ u_c,
            const float* __restrict__ theta_c,
            const float* __restrict__ len,
            const float* __restrict__ pE,
            const float* __restrict__ pA,
            const float* __restrict__ pI,
            const float* __restrict__ dir,
            int* __restrict__ cursor,        // this chunk's cursor row
            uint2* __restrict__ lists,
            int cs, int ce, int NB) {
    __shared__ uint2          slab[FSTG * 2];   // 32KB, records grouped by bucket
    __shared__ unsigned short sbk [FSTG * 2];   // 8KB, bucket id per slab slot
    __shared__ int hist [NBMAX];                // 4KB
    __shared__ int sc   [NBMAX];                // 4KB (inclusive scan)
    __shared__ int gpos [NBMAX];                // 4KB (global base per bucket)
    __shared__ int pbase[NBMAX];                // 4KB (consumed so far)

    int tid = threadIdx.x;
    int bs  = cs + blockIdx.x * FBE;
    int be  = bs + FBE; if (be > ce) be = ce;

    // ---- pass 1: count all block elements, reserve global runs once ----
    for (int b = tid; b < NBMAX; b += FTH) hist[b] = 0;
    __syncthreads();
    #pragma unroll
    for (int j = 0; j < FBE / FTH; ++j) {
        int e = bs + j * FTH + tid;
        if (e < be) {
            int2 cn = conn[e];
            atomicAdd(&hist[cn.x >> 10], 1);
            atomicAdd(&hist[cn.y >> 10], 1);
        }
    }
    __syncthreads();
    for (int b = tid; b < NB; b += FTH) {
        int c0 = hist[b];
        gpos[b]  = c0 ? atomicAdd(&cursor[b], c0) : 0;
        pbase[b] = 0;
    }
    __syncthreads();

    float uc = u_c[0];
    float tc = theta_c[0];

    // ---- stages: compute, block-sort into LDS, coalesced flush ----
    for (int st = 0; st < FBE / FSTG; ++st) {
        int ss = bs + st * FSTG;

        for (int b = tid; b < NBMAX; b += FTH) hist[b] = 0;
        __syncthreads();

        unsigned sv[2 * (FSTG / FTH)];
        uint2    rc[2 * (FSTG / FTH)];

        #pragma unroll
        for (int j = 0; j < FSTG / FTH; ++j) {
            int e = ss + j * FTH + tid;
            unsigned sa = 0xFFFFFFFFu, sb2 = 0xFFFFFFFFu;
            if (e < be) {
                int2 cn = conn[e];
                int na = cn.x, nb = cn.y;

                F3 pa_ = pred[na];
                F3 pb_ = pred[nb];

                float c  = dir[3 * e + 0];
                float s  = dir[3 * e + 2];
                float L  = len[e];
                float Ee = pE[e];
                float EA = Ee * pA[e];
                float EI = Ee * pI[e];

                float a0 = pa_.x * uc;
                float a1 = pa_.y * uc;
                float a2 = pa_.z * tc;
                float b0 = pb_.x * uc;
                float b1 = pb_.y * uc;
                float b2 = pb_.z * tc;

                float u_A  =  c * a0 + s * a1;
                float w_A  = -s * a0 + c * a1;
                float th_A = -a2;
                float u_B  =  c * b0 + s * b1;
                float w_B  = -s * b0 + c * b1;
                float th_B = -b2;

                float invL  = 1.0f / L;
                float ea_l  = EA * invL;            // AXIAL_WEIGHT = 1.0
                float ei_l  = EI * invL;
                float ei_l2 = ei_l  * invL;
                float ei_l3 = ei_l2 * invL;

                float dw = w_A - w_B;
                float f0 = ea_l * (u_A - u_B);
                float f1 = 12.0f * ei_l3 * dw + 6.0f * ei_l2 * (th_A + th_B);
                float f2 = 6.0f * ei_l2 * dw + 4.0f * ei_l * th_A + 2.0f * ei_l * th_B;
                float f5 = 6.0f * ei_l2 * dw + 2.0f * ei_l * th_A + 4.0f * ei_l * th_B;

                float fA0 = c * f0 - s * f1;
                float fA1 = s * f0 + c * f1;

                int bkA = na >> 10;
                int rA  = atomicAdd(&hist[bkA], 1);
                sa = ((unsigned)rA << 10) | (unsigned)bkA;
                rc[2 * j + 0] = packrec(fA0, fA1, -f2, na & 1023);

                int bkB = nb >> 10;
                int rB  = atomicAdd(&hist[bkB], 1);
                sb2 = ((unsigned)rB << 10) | (unsigned)bkB;
                rc[2 * j + 1] = packrec(-fA0, -fA1, -f5, nb & 1023);
            }
            sv[2 * j + 0] = sa;
            sv[2 * j + 1] = sb2;
        }
        __syncthreads();

        // inclusive block scan of stage hist (FTH == NBMAX == 1024)
        sc[tid] = hist[tid];
        __syncthreads();
        for (int off = 1; off < NBMAX; off <<= 1) {
            int v = (tid >= off) ? sc[tid - off] : 0;
            __syncthreads();
            sc[tid] += v;
            __syncthreads();
        }

        // place records grouped by bucket
        #pragma unroll
        for (int j = 0; j < 2 * (FSTG / FTH); ++j) {
            unsigned s2 = sv[j];
            if (s2 != 0xFFFFFFFFu) {
                int bk   = (int)(s2 & 1023u);
                int r    = (int)(s2 >> 10);
                int slot = sc[bk] - hist[bk] + r;
                slab[slot] = rc[j];
                sbk[slot]  = (unsigned short)bk;
            }
        }
        __syncthreads();

        // coalesced flush: consecutive slab slots -> consecutive global slots
        int total = sc[NBMAX - 1];
        for (int i = tid; i < total; i += FTH) {
            int bk = sbk[i];
            int g  = gpos[bk] + pbase[bk] + (i - (sc[bk] - hist[bk]));
            lists[g] = slab[i];
        }
        __syncthreads();

        for (int b = tid; b < NB; b += FTH) pbase[b] += hist[b];
        __syncthreads();
    }
}

__global__ void __launch_bounds__(512)
accum_kernel(const uint2* __restrict__ lists,
             const int* __restrict__ counts_c,
             const int* __restrict__ offsets_c,
             const float* __restrict__ Fext,
             const float* __restrict__ bcd,
             const float* __restrict__ bcr,
             double* __restrict__ acc,
             float* __restrict__ fint32,
             __half* __restrict__ fint16,
             int N, int isFirst, int isLast, int mode) {   // mode: 1 fp32, 2 fp16
    __shared__ float tile[SPAN * 3];
    __shared__ double sn[8], sd[8];

    int b = blockIdx.x;
    int nodeLo = b * SPAN;
    int gBase = nodeLo * 3;
    int gMax  = 3 * N;

    if (isFirst) {
        for (int i = threadIdx.x; i < SPAN * 3; i += 512) tile[i] = 0.0f;
    } else if (mode == 1) {
        for (int i = threadIdx.x; i < SPAN * 3; i += 512) {
            int g = gBase + i;
            tile[i] = (g < gMax) ? fint32[g] : 0.0f;
        }
    } else {
        for (int i = threadIdx.x; i < SPAN * 3; i += 512) {
            int g = gBase + i;
            tile[i] = (g < gMax) ? __half2float(fint16[g]) : 0.0f;
        }
    }
    __syncthreads();

    int cnt  = counts_c[b];
    int base = offsets_c[b];
    const uint2* L = lists + base;
    for (int r = threadIdx.x; r < cnt; r += 512) {
        uint2 rec = L[r];
        float fx = __half2float(__ushort_as_half((unsigned short)(rec.x & 0xFFFFu)));
        float fy = __half2float(__ushort_as_half((unsigned short)(rec.x >> 16)));
        float fz = __half2float(__ushort_as_half((unsigned short)(rec.y & 0xFFFFu)));
        int local = (int)(rec.y >> 16);
        atomicAdd(&tile[local * 3 + 0], fx);
        atomicAdd(&tile[local * 3 + 1], fy);
        atomicAdd(&tile[local * 3 + 2], fz);
    }
    __syncthreads();

    if (!isLast) {
        if (mode == 1) {
            for (int i = threadIdx.x; i < SPAN * 3; i += 512) {
                int g = gBase + i;
                if (g < gMax) fint32[g] = tile[i];
            }
        } else {
            for (int i = threadIdx.x; i < SPAN * 3; i += 512) {
                int g = gBase + i;
                if (g < gMax) fint16[g] = __float2half(tile[i]);
            }
        }
        return;
    }

    int spanCnt = N - nodeLo;
    if (spanCnt > SPAN) spanCnt = SPAN;

    double num = 0.0, den = 0.0;
    for (int l = threadIdx.x; l < spanCnt; l += 512) {
        int n = nodeLo + l;
        float md = 1.0f - bcd[n];
        float mr = 1.0f - bcr[n];
        float e0 = Fext[3 * n + 0];
        float e1 = Fext[3 * n + 1];
        float e2 = Fext[3 * n + 2];
        float r0 = (tile[l * 3 + 0] - e0) * md;
        float r1 = (tile[l * 3 + 1] - e1) * md;
        float r2 = (tile[l * 3 + 2] - e2) * mr;
        float g0 = e0 * md;
        float g1 = e1 * md;
        float g2 = e2 * mr;
        num += (double)r0 * r0 + (double)r1 * r1 + (double)r2 * r2;
        den += (double)g0 * g0 + (double)g1 * g1 + (double)g2 * g2;
    }
    #pragma unroll
    for (int off = 32; off > 0; off >>= 1) {
        num += __shfl_down(num, off, 64);
        den += __shfl_down(den, off, 64);
    }
    int lane = threadIdx.x & 63;
    int wv   = threadIdx.x >> 6;
    if (lane == 0) { sn[wv] = num; sd[wv] = den; }
    __syncthreads();
    if (threadIdx.x == 0) {
        double tn = 0.0, td = 0.0;
        for (int w = 0; w < 8; ++w) { tn += sn[w]; td += sd[w]; }
        atomicAdd(&acc[0], tn);
        atomicAdd(&acc[1], td);
    }
}

__global__ void final_kernel(const double* __restrict__ acc, float* __restrict__ out) {
    double den = acc[1];
    if (den < 1e-30) den = 1e-30;
    out[0] = (float)(acc[0] / den);
}

static inline size_t align256(size_t x) { return (x + 255) & ~(size_t)255; }

extern "C" void kernel_launch(void* const* d_in, const int* in_sizes, int n_in,
                              void* d_out, int out_size, void* d_ws, size_t ws_size,
                              hipStream_t stream) {
    const F3*    pred    = (const F3*)d_in[0];
    const float* u_c     = (const float*)d_in[1];
    const float* theta_c = (const float*)d_in[2];
    const float* len     = (const float*)d_in[3];
    const float* pE      = (const float*)d_in[4];
    const float* pA      = (const float*)d_in[5];
    const float* pI      = (const float*)d_in[6];
    const float* dir     = (const float*)d_in[7];
    const float* Fext    = (const float*)d_in[8];
    const float* bcd     = (const float*)d_in[9];
    const float* bcr     = (const float*)d_in[10];
    const int2*  conn    = (const int2*)d_in[11];

    int N = in_sizes[0] / 3;
    int E = in_sizes[3];
    int NB = (N + SPAN - 1) / SPAN;   // 977 for N=1M (must be <= NBMAX)

    // Config ladder: (K chunks, partial mode: 0 none / 1 fp32 / 2 fp16)
    const int cfgK[7] = {1, 2, 2, 4, 4, 8, 16};
    const int cfgM[7] = {0, 1, 2, 1, 2, 2, 2};
    int K = 16, mode = 2;
    size_t offF = 0, offL = 0;
    for (int t = 0; t < 7; ++t) {
        int Kc = cfgK[t], Mc = cfgM[t];
        int ce = (E + Kc - 1) / Kc;
        size_t meta = 256 + (size_t)3 * Kc * NB * 4;
        size_t oF = align256(meta);
        size_t fb = (Kc > 1) ? (size_t)3 * N * (Mc == 1 ? 4 : 2) : 0;
        size_t oL = align256(oF + fb);
        size_t need = oL + (size_t)2 * ce * 8;
        if (need <= ws_size) { K = Kc; mode = Mc; offF = oF; offL = oL; break; }
        if (t == 6) { K = Kc; mode = Mc; offF = oF; offL = oL; }
    }

    int chunkElems = (E + K - 1) / K;

    double* acc     = (double*)d_ws;
    int*    counts  = (int*)((char*)d_ws + 256);
    int*    offsets = counts + (size_t)K * NB;
    int*    cursors = offsets + (size_t)K * NB;
    float*  fint32  = (float*)((char*)d_ws + offF);
    __half* fint16  = (__half*)((char*)d_ws + offF);
    uint2*  lists   = (uint2*)((char*)d_ws + offL);

    hipMemsetAsync(d_ws, 0, 256 + (size_t)K * NB * 4, stream);

    int slabsPC = (chunkElems + 1024 * CEPB - 1) / (1024 * CEPB);
    count_kernel<<<K * slabsPC, 1024, 0, stream>>>(conn, counts, E, chunkElems, slabsPC, NB);

    scan_kernel<<<1, 1024, 0, stream>>>(counts, offsets, cursors, K, NB);

    for (int c = 0; c < K; ++c) {
        int cs = c * chunkElems;
        if (cs >= E) break;
        int ce = cs + chunkElems;
        if (ce > E) ce = E;
        int nfb = (ce - cs + FBE - 1) / FBE;

        fill_kernel<<<nfb, FTH, 0, stream>>>(
            conn, pred, u_c, theta_c, len, pE, pA, pI, dir,
            cursors + (size_t)c * NB, lists, cs, ce, NB);

        int isFirst = (c == 0);
        int isLast  = (ce == E);
        accum_kernel<<<NB, 512, 0, stream>>>(
            lists, counts + (size_t)c * NB, offsets + (size_t)c * NB,
            Fext, bcd, bcr, acc, fint32, fint16, N, isFirst, isLast, mode);
    }

    final_kernel<<<1, 1, 0, stream>>>(acc, (float*)d_out);
}

// Round 7
// 299.550 us; speedup vs baseline: 1.0602x; 1.0201x over previous
//
#include <hip/hip_runtime.h>
#include <hip/hip_fp16.h>

// 3-kernel exact-CSR scatter/gather:
//   count : conn pass -> counts[chunk][bucket]
//   fill  : block owns 4096 elems. Local wave-scan of counts -> global CSR
//           offsets (no scan kernel). ONE compute pass (element stream read
//           once, 8 gathers in flight), one cursor reservation per
//           (block,bucket), two LDS-sorted coalesced flush stages.
//           Records: 8B {fx16,fy16 | local16,fz16}.
//   accum : block per 1024-node bucket; derives its list offset by reducing
//           counts[0..b-1]; LDS fp32 tile; last chunk fuses masked loss; the
//           LAST block (device done-counter) writes the final scalar (no
//           final kernel).
// d_ws: [0:16) acc doubles | [16:20) done ctr | [256:) counts,cursors | lists

#define SPAN   1024
#define NBMAX  1024
#define CEPB   8
#define FTH    1024
#define FBE    4096

struct F3 { float x, y, z; };

__device__ __forceinline__ uint2 packrec(float fx, float fy, float fz, int local) {
    unsigned short hx = __half_as_ushort(__float2half(fx));
    unsigned short hy = __half_as_ushort(__float2half(fy));
    unsigned short hz = __half_as_ushort(__float2half(fz));
    return make_uint2(((unsigned)hy << 16) | hx, ((unsigned)local << 16) | hz);
}

// 1024-thread inclusive scan, 2 barriers. Caller must barrier before reusing
// wsum (all call sites below are separated by barriers).
__device__ __forceinline__ int block_incl_scan(int v, int* wsum, int lane, int wv) {
    #pragma unroll
    for (int off = 1; off < 64; off <<= 1) {
        int t = __shfl_up(v, off, 64);
        if (lane >= off) v += t;
    }
    if (lane == 63) wsum[wv] = v;
    __syncthreads();
    if (wv == 0) {
        int w = (lane < 16) ? wsum[lane] : 0;
        #pragma unroll
        for (int off = 1; off < 16; off <<= 1) {
            int t = __shfl_up(w, off, 64);
            if (lane >= off) w += t;
        }
        if (lane < 16) wsum[lane] = w;
    }
    __syncthreads();
    return v + ((wv > 0) ? wsum[wv - 1] : 0);
}

__global__ void __launch_bounds__(1024)
count_kernel(const int2* __restrict__ conn, int* __restrict__ counts,
             int E, int chunkElems, int slabsPC, int NB) {
    __shared__ int hist[NBMAX];
    int c = blockIdx.x / slabsPC;
    int s = blockIdx.x - c * slabsPC;
    int base = c * chunkElems + s * (1024 * CEPB);
    int end  = (c + 1) * chunkElems;
    if (end > E) end = E;

    hist[threadIdx.x] = 0;
    __syncthreads();

    #pragma unroll
    for (int i = 0; i < CEPB; ++i) {
        int e = base + i * 1024 + threadIdx.x;
        if (e < end) {
            int2 cn = conn[e];
            atomicAdd(&hist[cn.x >> 10], 1);
            atomicAdd(&hist[cn.y >> 10], 1);
        }
    }
    __syncthreads();

    int* cc = counts + (size_t)c * NB;
    if (threadIdx.x < NB) {
        int h = hist[threadIdx.x];
        if (h) atomicAdd(&cc[threadIdx.x], h);
    }
}

__global__ void __launch_bounds__(1024)
fill_kernel(const int2* __restrict__ conn,
            const F3*  __restrict__ pred,
            const float* __restrict__ u_c,
            const float* __restrict__ theta_c,
            const float* __restrict__ len,
            const float* __restrict__ pE,
            const float* __restrict__ pA,
            const float* __restrict__ pI,
            const float* __restrict__ dir,
            const int* __restrict__ counts_c,
            int* __restrict__ cursor_c,          // zero-initialized row
            uint2* __restrict__ lists,
            int cs, int ce, int NB) {
    __shared__ uint2          slab[FBE];     // 32KB (stage: 2048 elems -> 4096 recs)
    __shared__ unsigned short sbk [FBE];     // 8KB
    __shared__ int hist [NBMAX];
    __shared__ int hist2[NBMAX];
    __shared__ int boff [NBMAX];
    __shared__ int sc   [NBMAX];
    __shared__ int gpos [NBMAX];
    __shared__ int wsum [16];

    int tid = threadIdx.x, lane = tid & 63, wv = tid >> 6;

    // local exclusive scan of counts -> global CSR base per bucket
    hist[tid] = 0; hist2[tid] = 0;
    int cval = (tid < NB) ? counts_c[tid] : 0;
    int inc  = block_incl_scan(cval, wsum, lane, wv);
    boff[tid] = inc - cval;
    // (zeroing of hist/hist2 completed before scan's internal barriers)

    float uc = u_c[0];
    float tc = theta_c[0];
    int bs = cs + blockIdx.x * FBE;
    int be = bs + FBE; if (be > ce) be = ce;

    unsigned sv[8];   // (rank<<10)|bucket ; 0xFFFFFFFF = none
    uint2    rc[8];

    // single compute pass over all 4 elems/thread (stages split j<2 / j>=2)
    #pragma unroll
    for (int j = 0; j < 4; ++j) {
        int e = bs + j * FTH + tid;
        unsigned sa = 0xFFFFFFFFu, sb = 0xFFFFFFFFu;
        if (e < be) {
            int2 cn = conn[e];
            int na = cn.x, nb = cn.y;

            F3 pa_ = pred[na];
            F3 pb_ = pred[nb];

            float c  = dir[3 * e + 0];
            float s  = dir[3 * e + 2];
            float L  = len[e];
            float Ee = pE[e];
            float EA = Ee * pA[e];
            float EI = Ee * pI[e];

            float a0 = pa_.x * uc;
            float a1 = pa_.y * uc;
            float a2 = pa_.z * tc;
            float b0 = pb_.x * uc;
            float b1 = pb_.y * uc;
            float b2 = pb_.z * tc;

            float u_A  =  c * a0 + s * a1;
            float w_A  = -s * a0 + c * a1;
            float th_A = -a2;
            float u_B  =  c * b0 + s * b1;
            float w_B  = -s * b0 + c * b1;
            float th_B = -b2;

            float invL  = 1.0f / L;
            float ea_l  = EA * invL;             // AXIAL_WEIGHT = 1.0
            float ei_l  = EI * invL;
            float ei_l2 = ei_l  * invL;
            float ei_l3 = ei_l2 * invL;

            float dw = w_A - w_B;
            float f0 = ea_l * (u_A - u_B);
            float f1 = 12.0f * ei_l3 * dw + 6.0f * ei_l2 * (th_A + th_B);
            float f2 = 6.0f * ei_l2 * dw + 4.0f * ei_l * th_A + 2.0f * ei_l * th_B;
            float f5 = 6.0f * ei_l2 * dw + 2.0f * ei_l * th_A + 4.0f * ei_l * th_B;

            float fA0 = c * f0 - s * f1;
            float fA1 = s * f0 + c * f1;

            int* h = (j < 2) ? hist : hist2;

            int bkA = na >> 10;
            int rA  = atomicAdd(&h[bkA], 1);
            sa = ((unsigned)rA << 10) | (unsigned)bkA;
            rc[2 * j + 0] = packrec(fA0, fA1, -f2, na & 1023);

            int bkB = nb >> 10;
            int rB  = atomicAdd(&h[bkB], 1);
            sb = ((unsigned)rB << 10) | (unsigned)bkB;
            rc[2 * j + 1] = packrec(-fA0, -fA1, -f5, nb & 1023);
        }
        sv[2 * j + 0] = sa;
        sv[2 * j + 1] = sb;
    }
    __syncthreads();

    // one cursor reservation per (block,bucket)
    if (tid < NB) {
        int tot = hist[tid] + hist2[tid];
        gpos[tid] = tot ? (boff[tid] + atomicAdd(&cursor_c[tid], tot)) : 0;
    }

    // ---- stage 0: sort into LDS, coalesced flush ----
    int i0 = block_incl_scan(hist[tid], wsum, lane, wv);
    sc[tid] = i0;
    __syncthreads();
    #pragma unroll
    for (int r = 0; r < 4; ++r) {
        unsigned s2 = sv[r];
        if (s2 != 0xFFFFFFFFu) {
            int bk = (int)(s2 & 1023u);
            int rk = (int)(s2 >> 10);
            int slot = sc[bk] - hist[bk] + rk;
            slab[slot] = rc[r];
            sbk[slot]  = (unsigned short)bk;
        }
    }
    __syncthreads();
    int tot0 = sc[NBMAX - 1];
    for (int i = tid; i < tot0; i += FTH) {
        int bk = sbk[i];
        lists[gpos[bk] + (i - (sc[bk] - hist[bk]))] = slab[i];
    }
    __syncthreads();

    // ---- stage 1 ----
    int i1 = block_incl_scan(hist2[tid], wsum, lane, wv);
    sc[tid] = i1;
    __syncthreads();
    #pragma unroll
    for (int r = 4; r < 8; ++r) {
        unsigned s2 = sv[r];
        if (s2 != 0xFFFFFFFFu) {
            int bk = (int)(s2 & 1023u);
            int rk = (int)(s2 >> 10);
            int slot = sc[bk] - hist2[bk] + rk;
            slab[slot] = rc[r];
            sbk[slot]  = (unsigned short)bk;
        }
    }
    __syncthreads();
    int tot1 = sc[NBMAX - 1];
    for (int i = tid; i < tot1; i += FTH) {
        int bk = sbk[i];
        lists[gpos[bk] + hist[bk] + (i - (sc[bk] - hist2[bk]))] = slab[i];
    }
}

__global__ void __launch_bounds__(1024)
accum_kernel(const uint2* __restrict__ lists,
             const int* __restrict__ counts_c,
             const float* __restrict__ Fext,
             const float* __restrict__ bcd,
             const float* __restrict__ bcr,
             double* __restrict__ acc,
             unsigned int* __restrict__ done,
             float* __restrict__ fint32,
             __half* __restrict__ fint16,
             float* __restrict__ out,
             int N, int isFirst, int isLast, int mode, int nbGrid) {
    __shared__ float tile[SPAN * 3];
    __shared__ int ssum[16];
    __shared__ double sn[16], sd[16];

    int tid = threadIdx.x, lane = tid & 63, wv = tid >> 6;
    int b = blockIdx.x;
    int nodeLo = b * SPAN;
    int gBase = nodeLo * 3;
    int gMax  = 3 * N;

    // own list offset: reduce counts[0..b-1]
    int p = 0;
    for (int i = tid; i < b; i += FTH) p += counts_c[i];
    #pragma unroll
    for (int off = 32; off > 0; off >>= 1) p += __shfl_down(p, off, 64);
    if (lane == 0) ssum[wv] = p;

    if (isFirst) {
        for (int i = tid; i < SPAN * 3; i += FTH) tile[i] = 0.0f;
    } else if (mode == 1) {
        for (int i = tid; i < SPAN * 3; i += FTH) {
            int g = gBase + i;
            tile[i] = (g < gMax) ? fint32[g] : 0.0f;
        }
    } else {
        for (int i = tid; i < SPAN * 3; i += FTH) {
            int g = gBase + i;
            tile[i] = (g < gMax) ? __half2float(fint16[g]) : 0.0f;
        }
    }
    __syncthreads();

    int base = 0;
    #pragma unroll
    for (int w = 0; w < 16; ++w) base += ssum[w];

    int cnt = counts_c[b];
    const uint2* L = lists + base;
    for (int r = tid; r < cnt; r += FTH) {
        uint2 rec = L[r];
        float fx = __half2float(__ushort_as_half((unsigned short)(rec.x & 0xFFFFu)));
        float fy = __half2float(__ushort_as_half((unsigned short)(rec.x >> 16)));
        float fz = __half2float(__ushort_as_half((unsigned short)(rec.y & 0xFFFFu)));
        int local = (int)(rec.y >> 16);
        atomicAdd(&tile[local * 3 + 0], fx);
        atomicAdd(&tile[local * 3 + 1], fy);
        atomicAdd(&tile[local * 3 + 2], fz);
    }
    __syncthreads();

    if (!isLast) {
        if (mode == 1) {
            for (int i = tid; i < SPAN * 3; i += FTH) {
                int g = gBase + i;
                if (g < gMax) fint32[g] = tile[i];
            }
        } else {
            for (int i = tid; i < SPAN * 3; i += FTH) {
                int g = gBase + i;
                if (g < gMax) fint16[g] = __float2half(tile[i]);
            }
        }
        return;
    }

    // fused masked loss
    int spanCnt = N - nodeLo;
    if (spanCnt > SPAN) spanCnt = SPAN;

    double num = 0.0, den = 0.0;
    for (int l = tid; l < spanCnt; l += FTH) {
        int n = nodeLo + l;
        float md = 1.0f - bcd[n];
        float mr = 1.0f - bcr[n];
        float e0 = Fext[3 * n + 0];
        float e1 = Fext[3 * n + 1];
        float e2 = Fext[3 * n + 2];
        float r0 = (tile[l * 3 + 0] - e0) * md;
        float r1 = (tile[l * 3 + 1] - e1) * md;
        float r2 = (tile[l * 3 + 2] - e2) * mr;
        float g0 = e0 * md;
        float g1 = e1 * md;
        float g2 = e2 * mr;
        num += (double)r0 * r0 + (double)r1 * r1 + (double)r2 * r2;
        den += (double)g0 * g0 + (double)g1 * g1 + (double)g2 * g2;
    }
    #pragma unroll
    for (int off = 32; off > 0; off >>= 1) {
        num += __shfl_down(num, off, 64);
        den += __shfl_down(den, off, 64);
    }
    if (lane == 0) { sn[wv] = num; sd[wv] = den; }
    __syncthreads();
    if (tid == 0) {
        double tn = 0.0, td = 0.0;
        #pragma unroll
        for (int w = 0; w < 16; ++w) { tn += sn[w]; td += sd[w]; }
        atomicAdd(&acc[0], tn);
        atomicAdd(&acc[1], td);
        __threadfence();
        unsigned d = atomicAdd(done, 1u);
        if (d == (unsigned)(nbGrid - 1)) {
            double nume = atomicAdd(&acc[0], 0.0);   // device-scope coherent read
            double dene = atomicAdd(&acc[1], 0.0);
            if (dene < 1e-30) dene = 1e-30;
            out[0] = (float)(nume / dene);
        }
    }
}

static inline size_t align256(size_t x) { return (x + 255) & ~(size_t)255; }

extern "C" void kernel_launch(void* const* d_in, const int* in_sizes, int n_in,
                              void* d_out, int out_size, void* d_ws, size_t ws_size,
                              hipStream_t stream) {
    const F3*    pred    = (const F3*)d_in[0];
    const float* u_c     = (const float*)d_in[1];
    const float* theta_c = (const float*)d_in[2];
    const float* len     = (const float*)d_in[3];
    const float* pE      = (const float*)d_in[4];
    const float* pA      = (const float*)d_in[5];
    const float* pI      = (const float*)d_in[6];
    const float* dir     = (const float*)d_in[7];
    const float* Fext    = (const float*)d_in[8];
    const float* bcd     = (const float*)d_in[9];
    const float* bcr     = (const float*)d_in[10];
    const int2*  conn    = (const int2*)d_in[11];

    int N = in_sizes[0] / 3;
    int E = in_sizes[3];
    int NB = (N + SPAN - 1) / SPAN;   // must be <= NBMAX

    // Config ladder: (K chunks, partial mode: 0 none / 1 fp32 / 2 fp16)
    const int cfgK[7] = {1, 2, 2, 4, 4, 8, 16};
    const int cfgM[7] = {0, 1, 2, 1, 2, 2, 2};
    int K = 16, mode = 2;
    size_t offF = 0, offL = 0;
    for (int t = 0; t < 7; ++t) {
        int Kc = cfgK[t], Mc = cfgM[t];
        int ce = (E + Kc - 1) / Kc;
        size_t meta = 256 + (size_t)2 * Kc * NB * 4;   // counts + cursors
        size_t oF = align256(meta);
        size_t fb = (Kc > 1) ? (size_t)3 * N * (Mc == 1 ? 4 : 2) : 0;
        size_t oL = align256(oF + fb);
        size_t need = oL + (size_t)2 * ce * 8;
        if (need <= ws_size) { K = Kc; mode = Mc; offF = oF; offL = oL; break; }
        if (t == 6) { K = Kc; mode = Mc; offF = oF; offL = oL; }
    }

    int chunkElems = (E + K - 1) / K;

    double*       acc     = (double*)d_ws;
    unsigned int* done    = (unsigned int*)((char*)d_ws + 16);
    int*          counts  = (int*)((char*)d_ws + 256);
    int*          cursors = counts + (size_t)K * NB;
    float*        fint32  = (float*)((char*)d_ws + offF);
    __half*       fint16  = (__half*)((char*)d_ws + offF);
    uint2*        lists   = (uint2*)((char*)d_ws + offL);

    // zero acc + done + counts + cursors
    hipMemsetAsync(d_ws, 0, 256 + (size_t)2 * K * NB * 4, stream);

    int slabsPC = (chunkElems + 1024 * CEPB - 1) / (1024 * CEPB);
    count_kernel<<<K * slabsPC, 1024, 0, stream>>>(conn, counts, E, chunkElems, slabsPC, NB);

    for (int c = 0; c < K; ++c) {
        int cs = c * chunkElems;
        if (cs >= E) break;
        int ce = cs + chunkElems;
        if (ce > E) ce = E;
        int nfb = (ce - cs + FBE - 1) / FBE;

        fill_kernel<<<nfb, FTH, 0, stream>>>(
            conn, pred, u_c, theta_c, len, pE, pA, pI, dir,
            counts + (size_t)c * NB, cursors + (size_t)c * NB,
            lists, cs, ce, NB);

        int isFirst = (c == 0);
        int isLast  = (ce == E);
        accum_kernel<<<NB, 1024, 0, stream>>>(
            lists, counts + (size_t)c * NB,
            Fext, bcd, bcr, acc, done, fint32, fint16, (float*)d_out,
            N, isFirst, isLast, mode, NB);
    }
}

// Round 8
// 269.485 us; speedup vs baseline: 1.1785x; 1.1116x over previous
//
#include <hip/hip_runtime.h>
#include <hip/hip_fp16.h>

// Per-tile exclusive-region scatter/gather — NO global atomics anywhere in the
// hot path, no count/scan kernels, no memset:
//   fill  : block = one tile of 4096 elems -> exclusive 8192-record region.
//           Compute force once per element, LDS-sort records by 1024-node
//           bucket, coalesced flush, write per-tile ushort offset table
//           offs[NB+1]. Block 0 also zeroes the 64 loss-accumulator slots.
//   accum : block = one bucket; thread t replays tile t's segment
//           (offs[t][b]..offs[t][b+1], ~8 contiguous records) into LDS fp32
//           tile; fused masked loss -> 64 line-padded slot pairs (b&63).
//   final : 1 wave reduces the 64 slots, divides, writes out[0].
// Records: 8B {fx16,fy16 | local16,fz16}. K element-chunks + fp32/fp16 F_int
// partial chosen from ws_size (K=1 preferred; K=2/fp16 guaranteed to fit).

#define SPAN   1024
#define NBMAX  1024
#define OFFN   (NBMAX + 1)   // ushorts per tile offset row
#define FTH    1024          // fill threads
#define FBE    4096          // elems per fill tile
#define REGR   8192          // records per region (uint2)
#define ATH    512           // accum threads

struct F3 { float x, y, z; };

__device__ __forceinline__ uint2 packrec(float fx, float fy, float fz, int local) {
    unsigned short hx = __half_as_ushort(__float2half(fx));
    unsigned short hy = __half_as_ushort(__float2half(fy));
    unsigned short hz = __half_as_ushort(__float2half(fz));
    return make_uint2(((unsigned)hy << 16) | hx, ((unsigned)local << 16) | hz);
}

// 1024-thread inclusive scan. Call sites must be separated by __syncthreads().
__device__ __forceinline__ int block_incl_scan(int v, int* wsum, int lane, int wv) {
    #pragma unroll
    for (int off = 1; off < 64; off <<= 1) {
        int t = __shfl_up(v, off, 64);
        if (lane >= off) v += t;
    }
    if (lane == 63) wsum[wv] = v;
    __syncthreads();
    if (wv == 0) {
        int w = (lane < 16) ? wsum[lane] : 0;
        #pragma unroll
        for (int off = 1; off < 16; off <<= 1) {
            int t = __shfl_up(w, off, 64);
            if (lane >= off) w += t;
        }
        if (lane < 16) wsum[lane] = w;
    }
    __syncthreads();
    return v + ((wv > 0) ? wsum[wv - 1] : 0);
}

__global__ void __launch_bounds__(1024)
fill_kernel(const int2* __restrict__ conn,
            const F3*  __restrict__ pred,
            const float* __restrict__ u_c,
            const float* __restrict__ theta_c,
            const float* __restrict__ len,
            const float* __restrict__ pE,
            const float* __restrict__ pA,
            const float* __restrict__ pI,
            const float* __restrict__ dir,
            uint2* __restrict__ regions,
            unsigned short* __restrict__ offsTab,
            double* __restrict__ accSlots,
            int cs, int ce, int NB) {
    __shared__ uint2          slab[FBE];    // 32KB: one stage (2048 elems -> 4096 recs)
    __shared__ unsigned short sbk [FBE];    // 8KB
    __shared__ int hist0[NBMAX];
    __shared__ int hist1[NBMAX];
    __shared__ int boff [NBMAX];
    __shared__ int sc   [NBMAX];
    __shared__ int wsum [16];

    int tid = threadIdx.x, lane = tid & 63, wv = tid >> 6;

    if (blockIdx.x == 0 && tid < 512) accSlots[tid] = 0.0;  // 64 slots * 64B

    hist0[tid] = 0;
    hist1[tid] = 0;
    __syncthreads();

    float uc = u_c[0];
    float tc = theta_c[0];
    int bs = cs + blockIdx.x * FBE;
    int be = bs + FBE; if (be > ce) be = ce;

    unsigned sv[8];   // (rank<<10)|bucket ; 0xFFFFFFFF = none
    uint2    rc[8];

    #pragma unroll
    for (int j = 0; j < 4; ++j) {
        int e = bs + j * FTH + tid;
        unsigned sa = 0xFFFFFFFFu, sb = 0xFFFFFFFFu;
        if (e < be) {
            int2 cn = conn[e];
            int na = cn.x, nb = cn.y;

            F3 pa_ = pred[na];
            F3 pb_ = pred[nb];

            float c  = dir[3 * e + 0];
            float s  = dir[3 * e + 2];
            float L  = len[e];
            float Ee = pE[e];
            float EA = Ee * pA[e];
            float EI = Ee * pI[e];

            float a0 = pa_.x * uc;
            float a1 = pa_.y * uc;
            float a2 = pa_.z * tc;
            float b0 = pb_.x * uc;
            float b1 = pb_.y * uc;
            float b2 = pb_.z * tc;

            float u_A  =  c * a0 + s * a1;
            float w_A  = -s * a0 + c * a1;
            float th_A = -a2;
            float u_B  =  c * b0 + s * b1;
            float w_B  = -s * b0 + c * b1;
            float th_B = -b2;

            float invL  = 1.0f / L;
            float ea_l  = EA * invL;             // AXIAL_WEIGHT = 1.0
            float ei_l  = EI * invL;
            float ei_l2 = ei_l  * invL;
            float ei_l3 = ei_l2 * invL;

            float dw = w_A - w_B;
            float f0 = ea_l * (u_A - u_B);
            float f1 = 12.0f * ei_l3 * dw + 6.0f * ei_l2 * (th_A + th_B);
            float f2 = 6.0f * ei_l2 * dw + 4.0f * ei_l * th_A + 2.0f * ei_l * th_B;
            float f5 = 6.0f * ei_l2 * dw + 2.0f * ei_l * th_A + 4.0f * ei_l * th_B;

            float fA0 = c * f0 - s * f1;
            float fA1 = s * f0 + c * f1;

            int* h = (j < 2) ? hist0 : hist1;

            int bkA = na >> 10;
            int rA  = atomicAdd(&h[bkA], 1);
            sa = ((unsigned)rA << 10) | (unsigned)bkA;
            rc[2 * j + 0] = packrec(fA0, fA1, -f2, na & 1023);

            int bkB = nb >> 10;
            int rB  = atomicAdd(&h[bkB], 1);
            sb = ((unsigned)rB << 10) | (unsigned)bkB;
            rc[2 * j + 1] = packrec(-fA0, -fA1, -f5, nb & 1023);
        }
        sv[2 * j + 0] = sa;
        sv[2 * j + 1] = sb;
    }
    __syncthreads();

    // combined scan -> per-bucket region offsets; emit ushort offset table
    int h0 = hist0[tid], h1 = hist1[tid];
    int tot = h0 + h1;
    int iF = block_incl_scan(tot, wsum, lane, wv);
    boff[tid] = iF - tot;
    sc[tid]   = iF;
    __syncthreads();

    unsigned short* offs = offsTab + (size_t)blockIdx.x * OFFN;
    if (tid < NB) offs[tid] = (unsigned short)boff[tid];
    if (tid == 0) offs[NB]  = (unsigned short)sc[NB - 1];

    uint2* regbase = regions + (size_t)blockIdx.x * REGR;

    // ---- stage 0 ----
    int i0 = block_incl_scan(h0, wsum, lane, wv);
    sc[tid] = i0;
    __syncthreads();
    #pragma unroll
    for (int r = 0; r < 4; ++r) {
        unsigned s2 = sv[r];
        if (s2 != 0xFFFFFFFFu) {
            int bk = (int)(s2 & 1023u);
            int rk = (int)(s2 >> 10);
            int slot = sc[bk] - hist0[bk] + rk;
            slab[slot] = rc[r];
            sbk[slot]  = (unsigned short)bk;
        }
    }
    __syncthreads();
    int tot0 = sc[NBMAX - 1];
    for (int i = tid; i < tot0; i += FTH) {
        int bk = sbk[i];
        regbase[boff[bk] + (i - (sc[bk] - hist0[bk]))] = slab[i];
    }
    __syncthreads();

    // ---- stage 1 ----
    int i1 = block_incl_scan(h1, wsum, lane, wv);
    sc[tid] = i1;
    __syncthreads();
    #pragma unroll
    for (int r = 4; r < 8; ++r) {
        unsigned s2 = sv[r];
        if (s2 != 0xFFFFFFFFu) {
            int bk = (int)(s2 & 1023u);
            int rk = (int)(s2 >> 10);
            int slot = sc[bk] - hist1[bk] + rk;
            slab[slot] = rc[r];
            sbk[slot]  = (unsigned short)bk;
        }
    }
    __syncthreads();
    int tot1 = sc[NBMAX - 1];
    for (int i = tid; i < tot1; i += FTH) {
        int bk = sbk[i];
        regbase[boff[bk] + hist0[bk] + (i - (sc[bk] - hist1[bk]))] = slab[i];
    }
}

__global__ void __launch_bounds__(512)
accum_kernel(const uint2* __restrict__ regions,
             const unsigned short* __restrict__ offsTab,
             const float* __restrict__ Fext,
             const float* __restrict__ bcd,
             const float* __restrict__ bcr,
             double* __restrict__ accSlots,
             float* __restrict__ fint32,
             __half* __restrict__ fint16,
             int N, int NB, int NT, int isFirst, int isLast, int mode) {
    __shared__ float tile[SPAN * 3];
    __shared__ double sn[8], sd[8];

    int tid = threadIdx.x, lane = tid & 63, wv = tid >> 6;
    int b = blockIdx.x;
    int nodeLo = b * SPAN;
    int gBase = nodeLo * 3;
    int gMax  = 3 * N;

    if (isFirst) {
        for (int i = tid; i < SPAN * 3; i += ATH) tile[i] = 0.0f;
    } else if (mode == 1) {
        for (int i = tid; i < SPAN * 3; i += ATH) {
            int g = gBase + i;
            tile[i] = (g < gMax) ? fint32[g] : 0.0f;
        }
    } else {
        for (int i = tid; i < SPAN * 3; i += ATH) {
            int g = gBase + i;
            tile[i] = (g < gMax) ? __half2float(fint16[g]) : 0.0f;
        }
    }
    __syncthreads();

    // thread t replays tile t's segment for this bucket
    if (tid < NT) {
        const unsigned short* o = offsTab + (size_t)tid * OFFN + b;
        int s0 = o[0];
        int s1 = o[1];
        const uint2* reg = regions + (size_t)tid * REGR;
        for (int i = s0; i < s1; ++i) {
            uint2 rec = reg[i];
            float fx = __half2float(__ushort_as_half((unsigned short)(rec.x & 0xFFFFu)));
            float fy = __half2float(__ushort_as_half((unsigned short)(rec.x >> 16)));
            float fz = __half2float(__ushort_as_half((unsigned short)(rec.y & 0xFFFFu)));
            int local = (int)(rec.y >> 16);
            atomicAdd(&tile[local * 3 + 0], fx);
            atomicAdd(&tile[local * 3 + 1], fy);
            atomicAdd(&tile[local * 3 + 2], fz);
        }
    }
    __syncthreads();

    if (!isLast) {
        if (mode == 1) {
            for (int i = tid; i < SPAN * 3; i += ATH) {
                int g = gBase + i;
                if (g < gMax) fint32[g] = tile[i];
            }
        } else {
            for (int i = tid; i < SPAN * 3; i += ATH) {
                int g = gBase + i;
                if (g < gMax) fint16[g] = __float2half(tile[i]);
            }
        }
        return;
    }

    // fused masked loss over this bucket's node range
    int spanCnt = N - nodeLo;
    if (spanCnt > SPAN) spanCnt = SPAN;

    double num = 0.0, den = 0.0;
    for (int l = tid; l < spanCnt; l += ATH) {
        int n = nodeLo + l;
        float md = 1.0f - bcd[n];
        float mr = 1.0f - bcr[n];
        float e0 = Fext[3 * n + 0];
        float e1 = Fext[3 * n + 1];
        float e2 = Fext[3 * n + 2];
        float r0 = (tile[l * 3 + 0] - e0) * md;
        float r1 = (tile[l * 3 + 1] - e1) * md;
        float r2 = (tile[l * 3 + 2] - e2) * mr;
        float g0 = e0 * md;
        float g1 = e1 * md;
        float g2 = e2 * mr;
        num += (double)r0 * r0 + (double)r1 * r1 + (double)r2 * r2;
        den += (double)g0 * g0 + (double)g1 * g1 + (double)g2 * g2;
    }
    #pragma unroll
    for (int off = 32; off > 0; off >>= 1) {
        num += __shfl_down(num, off, 64);
        den += __shfl_down(den, off, 64);
    }
    if (lane == 0) { sn[wv] = num; sd[wv] = den; }
    __syncthreads();
    if (tid == 0) {
        double tn = 0.0, td = 0.0;
        #pragma unroll
        for (int w = 0; w < 8; ++w) { tn += sn[w]; td += sd[w]; }
        // spread over 64 line-padded slot pairs: max ~16 same-line RMWs
        double* slot = accSlots + (size_t)(b & 63) * 8;
        atomicAdd(&slot[0], tn);
        atomicAdd(&slot[1], td);
    }
}

__global__ void final_kernel(const double* __restrict__ accSlots,
                             float* __restrict__ out) {
    int t = threadIdx.x;   // 64 threads
    double n = accSlots[t * 8 + 0];
    double d = accSlots[t * 8 + 1];
    #pragma unroll
    for (int off = 32; off > 0; off >>= 1) {
        n += __shfl_down(n, off, 64);
        d += __shfl_down(d, off, 64);
    }
    if (t == 0) {
        if (d < 1e-30) d = 1e-30;
        out[0] = (float)(n / d);
    }
}

static inline size_t align256(size_t x) { return (x + 255) & ~(size_t)255; }

extern "C" void kernel_launch(void* const* d_in, const int* in_sizes, int n_in,
                              void* d_out, int out_size, void* d_ws, size_t ws_size,
                              hipStream_t stream) {
    const F3*    pred    = (const F3*)d_in[0];
    const float* u_c     = (const float*)d_in[1];
    const float* theta_c = (const float*)d_in[2];
    const float* len     = (const float*)d_in[3];
    const float* pE      = (const float*)d_in[4];
    const float* pA      = (const float*)d_in[5];
    const float* pI      = (const float*)d_in[6];
    const float* dir     = (const float*)d_in[7];
    const float* Fext    = (const float*)d_in[8];
    const float* bcd     = (const float*)d_in[9];
    const float* bcr     = (const float*)d_in[10];
    const int2*  conn    = (const int2*)d_in[11];

    int N = in_sizes[0] / 3;
    int E = in_sizes[3];
    int NB = (N + SPAN - 1) / SPAN;   // must be <= NBMAX

    // Config ladder: (K chunks, partial mode: 0 none / 1 fp32 / 2 fp16)
    const int cfgK[7] = {1, 2, 2, 4, 4, 8, 16};
    const int cfgM[7] = {0, 1, 2, 1, 2, 2, 2};
    int K = 16, mode = 2;
    size_t oOff = 4096, oF = 0, oR = 0;
    for (int t = 0; t < 7; ++t) {
        int Kc = cfgK[t], Mc = cfgM[t];
        int ce = (E + Kc - 1) / Kc;
        int NTc = (ce + FBE - 1) / FBE;
        size_t offB = (size_t)NTc * OFFN * 2;
        size_t oFt  = align256(oOff + offB);
        size_t fb   = (Kc > 1) ? (size_t)3 * N * (Mc == 1 ? 4 : 2) : 0;
        size_t oRt  = align256(oFt + fb);
        size_t need = oRt + (size_t)NTc * REGR * 8;
        if (need <= ws_size || t == 6) {
            K = Kc; mode = Mc; oF = oFt; oR = oRt;
            if (need <= ws_size) break;
        }
    }

    int chunkElems = (E + K - 1) / K;

    double*         accSlots = (double*)d_ws;                 // 64 slots * 64B
    unsigned short* offsTab  = (unsigned short*)((char*)d_ws + oOff);
    float*          fint32   = (float*)((char*)d_ws + oF);
    __half*         fint16   = (__half*)((char*)d_ws + oF);
    uint2*          regions  = (uint2*)((char*)d_ws + oR);

    for (int c = 0; c < K; ++c) {
        int cs = c * chunkElems;
        if (cs >= E) break;
        int ce = cs + chunkElems;
        if (ce > E) ce = E;
        int NT = (ce - cs + FBE - 1) / FBE;

        fill_kernel<<<NT, FTH, 0, stream>>>(
            conn, pred, u_c, theta_c, len, pE, pA, pI, dir,
            regions, offsTab, accSlots, cs, ce, NB);

        int isFirst = (c == 0);
        int isLast  = (ce == E);
        accum_kernel<<<NB, ATH, 0, stream>>>(
            regions, offsTab, Fext, bcd, bcr, accSlots,
            fint32, fint16, N, NB, NT, isFirst, isLast, mode);
    }

    final_kernel<<<1, 64, 0, stream>>>(accSlots, (float*)d_out);
}